// Round 4
// baseline (2085.437 us; speedup 1.0000x reference)
//
#include <hip/hip_runtime.h>
#include <hip/hip_bf16.h>
#include <cmath>

#define TBL (1 << 19)   // T = 2^19 hash table entries per level (power of two)

__device__ __forceinline__ float relu_f(float x) { return fmaxf(x, 0.0f); }

// res_l = floor(16 * 1.3819^l); dense iff (res+1)^3 <= 2^19  (l = 0..4)
#define RES_LIST {16, 22, 30, 42, 58, 80, 111, 153, 212, 294, 406, 561, 775, 1072, 1481, 2047}

// ---------------------------------------------------------------------------
// Kernel 1: hash-grid encode. One thread per point, all 16 levels.
// No persistent feature array: each level's (a0,a1) goes straight to ws,
// layout ws_enc[l*n + i] (float2) so both stores here and loads in mlp_kernel
// are coalesced. launch_bounds(256,8) caps VGPRs at 64 -> 8 waves/SIMD, which
// is what hides the ~200-900 cyc gather latency (R2->R3 showed BW scales
// linearly with occupancy => latency-bound, not BW-ceiling-bound).
// ---------------------------------------------------------------------------
__global__ __launch_bounds__(256, 8)
void encode_kernel(const float* __restrict__ xyz,
                   const float* __restrict__ table,
                   float2* __restrict__ ws_enc,
                   int n)
{
    constexpr unsigned RES[16] = RES_LIST;

    const int i = blockIdx.x * 256 + threadIdx.x;
    if (i >= n) return;

    const float px_ = xyz[3 * (size_t)i + 0];
    const float py_ = xyz[3 * (size_t)i + 1];
    const float pz_ = xyz[3 * (size_t)i + 2];

#pragma unroll
    for (int l = 0; l < 16; ++l) {
        const unsigned res = RES[l];
        const float fr = (float)res;
        const float posx = px_ * fr, posy = py_ * fr, posz = pz_ * fr;
        const float fx = floorf(posx), fy = floorf(posy), fz = floorf(posz);
        const float wx = posx - fx, wy = posy - fy, wz = posz - fz;
        const unsigned x0 = (unsigned)fx, y0 = (unsigned)fy, z0 = (unsigned)fz;
        const float* tb = table + (size_t)l * (TBL * 2);
        float a0 = 0.0f, a1 = 0.0f;
#pragma unroll
        for (int c = 0; c < 8; ++c) {
            const unsigned cx = x0 + (c & 1);
            const unsigned cy = y0 + ((c >> 1) & 1);
            const unsigned cz = z0 + ((c >> 2) & 1);
            unsigned idx;
            if (l < 5) {
                const unsigned s = res + 1u;
                idx = cx + cy * s + cz * (s * s);
            } else {
                idx = (cx * 1u) ^ (cy * 2654435761u) ^ (cz * 805459861u);
                idx &= (unsigned)(TBL - 1);
            }
            const float w = ((c & 1) ? wx : 1.0f - wx) *
                            ((c & 2) ? wy : 1.0f - wy) *
                            ((c & 4) ? wz : 1.0f - wz);
            const float2 f = *reinterpret_cast<const float2*>(tb + 2u * idx);
            a0 = fmaf(f.x, w, a0);
            a1 = fmaf(f.y, w, a1);
        }
        ws_enc[(size_t)l * n + i] = make_float2(a0, a1);
    }
}

// ---------------------------------------------------------------------------
// Kernel 2: the MLPs. One thread per point; enc streamed from ws (two k-steps
// per float2 load), so the largest live set is one activation array at a time.
// VALU-bound; occupancy 4 waves/SIMD is plenty with no gathers to hide.
// ---------------------------------------------------------------------------
__global__ __launch_bounds__(256, 4)
void mlp_kernel(const float2* __restrict__ ws_enc,
                const float* __restrict__ dirv,
                const float* __restrict__ ws1,   // (32,64)
                const float* __restrict__ ws2,   // (64,17)
                const float* __restrict__ wr1,   // (32,64)
                const float* __restrict__ wr2,   // (64,64)
                const float* __restrict__ wr3,   // (64,3)
                float* __restrict__ out,
                int n)
{
    const int i = blockIdx.x * 256 + threadIdx.x;
    if (i >= n) return;

    // ---------------- sigma MLP: enc(32) -> 64 -> 17 ----------------
    float h[64];
#pragma unroll
    for (int j = 0; j < 64; ++j) h[j] = 0.0f;
#pragma unroll
    for (int l = 0; l < 16; ++l) {
        const float2 e = ws_enc[(size_t)l * n + i];
#pragma unroll
        for (int j = 0; j < 64; ++j) h[j] = fmaf(e.x, ws1[(2 * l) * 64 + j], h[j]);
#pragma unroll
        for (int j = 0; j < 64; ++j) h[j] = fmaf(e.y, ws1[(2 * l + 1) * 64 + j], h[j]);
    }
#pragma unroll
    for (int j = 0; j < 64; ++j) h[j] = relu_f(h[j]);

    float geo[17];
#pragma unroll
    for (int j = 0; j < 17; ++j) geo[j] = 0.0f;
#pragma unroll
    for (int k = 0; k < 64; ++k) {
        const float e = h[k];
#pragma unroll
        for (int j = 0; j < 17; ++j) geo[j] = fmaf(e, ws2[k * 17 + j], geo[j]);
    }
    out[3 * (size_t)n + (size_t)i] = relu_f(geo[0]);
    // h[] dead from here

    // ---------------- SH deg-4 of dir*2-1 ----------------
    const float dx = dirv[3 * (size_t)i + 0] * 2.0f - 1.0f;
    const float dy = dirv[3 * (size_t)i + 1] * 2.0f - 1.0f;
    const float dz = dirv[3 * (size_t)i + 2] * 2.0f - 1.0f;
    const float x2 = dx * dx, y2 = dy * dy, z2 = dz * dz;
    const float xy = dx * dy, yz = dy * dz, xz = dx * dz;

    float sh[16];
    sh[0]  = 0.28209479177387814f;
    sh[1]  = -0.48860251190291987f * dy;
    sh[2]  = 0.48860251190291987f * dz;
    sh[3]  = -0.48860251190291987f * dx;
    sh[4]  = 1.0925484305920792f * xy;
    sh[5]  = -1.0925484305920792f * yz;
    sh[6]  = 0.94617469575756f * z2 - 0.31539156525252f;
    sh[7]  = -1.0925484305920792f * xz;
    sh[8]  = 0.5462742152960396f * (x2 - y2);
    sh[9]  = 0.5900435899266435f * dy * (-3.0f * x2 + y2);
    sh[10] = 2.890611442640554f * xy * dz;
    sh[11] = 0.4570457994644657f * dy * (1.0f - 5.0f * z2);
    sh[12] = 0.3731763325901154f * dz * (5.0f * z2 - 3.0f);
    sh[13] = 0.4570457994644657f * dx * (1.0f - 5.0f * z2);
    sh[14] = 1.445305721320277f * dz * (x2 - y2);
    sh[15] = 0.5900435899266435f * dx * (-x2 + 3.0f * y2);

    // ---------------- rgb MLP: [sh(16) | geo[1..17](16)] -> 64 -> 64 -> 3 ----
    float g[64];
#pragma unroll
    for (int j = 0; j < 64; ++j) g[j] = 0.0f;
#pragma unroll
    for (int k = 0; k < 16; ++k) {
        const float e = sh[k];
#pragma unroll
        for (int j = 0; j < 64; ++j) g[j] = fmaf(e, wr1[k * 64 + j], g[j]);
    }
#pragma unroll
    for (int k = 16; k < 32; ++k) {
        const float e = geo[k - 15];   // geo_feat[k-16] = geo[k-16+1]
#pragma unroll
        for (int j = 0; j < 64; ++j) g[j] = fmaf(e, wr1[k * 64 + j], g[j]);
    }
#pragma unroll
    for (int j = 0; j < 64; ++j) g[j] = relu_f(g[j]);
    // sh[], geo[] dead from here

    // rgb layer 2 in two 32-neuron halves to cap live registers at ~g[64]+32
    float r0 = 0.0f, r1 = 0.0f, r2 = 0.0f;
#pragma unroll
    for (int half = 0; half < 2; ++half) {
        const int j0 = half * 32;
        float g2h[32];
#pragma unroll
        for (int j = 0; j < 32; ++j) g2h[j] = 0.0f;
#pragma unroll
        for (int k = 0; k < 64; ++k) {
            const float e = g[k];
#pragma unroll
            for (int j = 0; j < 32; ++j) g2h[j] = fmaf(e, wr2[k * 64 + j0 + j], g2h[j]);
        }
#pragma unroll
        for (int j = 0; j < 32; ++j) {
            const float e = relu_f(g2h[j]);
            r0 = fmaf(e, wr3[(j0 + j) * 3 + 0], r0);
            r1 = fmaf(e, wr3[(j0 + j) * 3 + 1], r1);
            r2 = fmaf(e, wr3[(j0 + j) * 3 + 2], r2);
        }
    }

    out[3 * (size_t)i + 0] = 1.0f / (1.0f + __expf(-r0));
    out[3 * (size_t)i + 1] = 1.0f / (1.0f + __expf(-r1));
    out[3 * (size_t)i + 2] = 1.0f / (1.0f + __expf(-r2));
}

// ---------------------------------------------------------------------------
// Fallback: round-3 fused kernel (used only if ws_size can't hold enc).
// ---------------------------------------------------------------------------
__global__ __launch_bounds__(256, 4)
void nerf_fused(const float* __restrict__ xyz,
                const float* __restrict__ dirv,
                const float* __restrict__ table,
                const float* __restrict__ ws1,
                const float* __restrict__ ws2,
                const float* __restrict__ wr1,
                const float* __restrict__ wr2,
                const float* __restrict__ wr3,
                float* __restrict__ out,
                int n)
{
    constexpr unsigned RES[16] = RES_LIST;

    const int i = blockIdx.x * 256 + threadIdx.x;
    if (i >= n) return;

    const float px_ = xyz[3 * (size_t)i + 0];
    const float py_ = xyz[3 * (size_t)i + 1];
    const float pz_ = xyz[3 * (size_t)i + 2];

    float enc[32];
#pragma unroll
    for (int l = 0; l < 16; ++l) {
        const unsigned res = RES[l];
        const float fr = (float)res;
        const float posx = px_ * fr, posy = py_ * fr, posz = pz_ * fr;
        const float fx = floorf(posx), fy = floorf(posy), fz = floorf(posz);
        const float wx = posx - fx, wy = posy - fy, wz = posz - fz;
        const unsigned x0 = (unsigned)fx, y0 = (unsigned)fy, z0 = (unsigned)fz;
        const float* tb = table + (size_t)l * (TBL * 2);
        float a0 = 0.0f, a1 = 0.0f;
#pragma unroll
        for (int c = 0; c < 8; ++c) {
            const unsigned cx = x0 + (c & 1);
            const unsigned cy = y0 + ((c >> 1) & 1);
            const unsigned cz = z0 + ((c >> 2) & 1);
            unsigned idx;
            if (l < 5) {
                const unsigned s = res + 1u;
                idx = cx + cy * s + cz * (s * s);
            } else {
                idx = (cx * 1u) ^ (cy * 2654435761u) ^ (cz * 805459861u);
                idx &= (unsigned)(TBL - 1);
            }
            const float w = ((c & 1) ? wx : 1.0f - wx) *
                            ((c & 2) ? wy : 1.0f - wy) *
                            ((c & 4) ? wz : 1.0f - wz);
            const float2 f = *reinterpret_cast<const float2*>(tb + 2u * idx);
            a0 = fmaf(f.x, w, a0);
            a1 = fmaf(f.y, w, a1);
        }
        enc[2 * l + 0] = a0;
        enc[2 * l + 1] = a1;
    }

    float h[64];
#pragma unroll
    for (int j = 0; j < 64; ++j) h[j] = 0.0f;
#pragma unroll
    for (int k = 0; k < 32; ++k) {
        const float e = enc[k];
#pragma unroll
        for (int j = 0; j < 64; ++j) h[j] = fmaf(e, ws1[k * 64 + j], h[j]);
    }
#pragma unroll
    for (int j = 0; j < 64; ++j) h[j] = relu_f(h[j]);

    float geo[17];
#pragma unroll
    for (int j = 0; j < 17; ++j) geo[j] = 0.0f;
#pragma unroll
    for (int k = 0; k < 64; ++k) {
        const float e = h[k];
#pragma unroll
        for (int j = 0; j < 17; ++j) geo[j] = fmaf(e, ws2[k * 17 + j], geo[j]);
    }
    out[3 * (size_t)n + (size_t)i] = relu_f(geo[0]);

    const float dx = dirv[3 * (size_t)i + 0] * 2.0f - 1.0f;
    const float dy = dirv[3 * (size_t)i + 1] * 2.0f - 1.0f;
    const float dz = dirv[3 * (size_t)i + 2] * 2.0f - 1.0f;
    const float x2 = dx * dx, y2 = dy * dy, z2 = dz * dz;
    const float xy = dx * dy, yz = dy * dz, xz = dx * dz;

    float sh[16];
    sh[0]  = 0.28209479177387814f;
    sh[1]  = -0.48860251190291987f * dy;
    sh[2]  = 0.48860251190291987f * dz;
    sh[3]  = -0.48860251190291987f * dx;
    sh[4]  = 1.0925484305920792f * xy;
    sh[5]  = -1.0925484305920792f * yz;
    sh[6]  = 0.94617469575756f * z2 - 0.31539156525252f;
    sh[7]  = -1.0925484305920792f * xz;
    sh[8]  = 0.5462742152960396f * (x2 - y2);
    sh[9]  = 0.5900435899266435f * dy * (-3.0f * x2 + y2);
    sh[10] = 2.890611442640554f * xy * dz;
    sh[11] = 0.4570457994644657f * dy * (1.0f - 5.0f * z2);
    sh[12] = 0.3731763325901154f * dz * (5.0f * z2 - 3.0f);
    sh[13] = 0.4570457994644657f * dx * (1.0f - 5.0f * z2);
    sh[14] = 1.445305721320277f * dz * (x2 - y2);
    sh[15] = 0.5900435899266435f * dx * (-x2 + 3.0f * y2);

    float g[64];
#pragma unroll
    for (int j = 0; j < 64; ++j) g[j] = 0.0f;
#pragma unroll
    for (int k = 0; k < 16; ++k) {
        const float e = sh[k];
#pragma unroll
        for (int j = 0; j < 64; ++j) g[j] = fmaf(e, wr1[k * 64 + j], g[j]);
    }
#pragma unroll
    for (int k = 16; k < 32; ++k) {
        const float e = geo[k - 15];
#pragma unroll
        for (int j = 0; j < 64; ++j) g[j] = fmaf(e, wr1[k * 64 + j], g[j]);
    }
#pragma unroll
    for (int j = 0; j < 64; ++j) g[j] = relu_f(g[j]);

    float r0 = 0.0f, r1 = 0.0f, r2 = 0.0f;
#pragma unroll
    for (int half = 0; half < 2; ++half) {
        const int j0 = half * 32;
        float g2h[32];
#pragma unroll
        for (int j = 0; j < 32; ++j) g2h[j] = 0.0f;
#pragma unroll
        for (int k = 0; k < 64; ++k) {
            const float e = g[k];
#pragma unroll
            for (int j = 0; j < 32; ++j) g2h[j] = fmaf(e, wr2[k * 64 + j0 + j], g2h[j]);
        }
#pragma unroll
        for (int j = 0; j < 32; ++j) {
            const float e = relu_f(g2h[j]);
            r0 = fmaf(e, wr3[(j0 + j) * 3 + 0], r0);
            r1 = fmaf(e, wr3[(j0 + j) * 3 + 1], r1);
            r2 = fmaf(e, wr3[(j0 + j) * 3 + 2], r2);
        }
    }

    out[3 * (size_t)i + 0] = 1.0f / (1.0f + __expf(-r0));
    out[3 * (size_t)i + 1] = 1.0f / (1.0f + __expf(-r1));
    out[3 * (size_t)i + 2] = 1.0f / (1.0f + __expf(-r2));
}

extern "C" void kernel_launch(void* const* d_in, const int* in_sizes, int n_in,
                              void* d_out, int out_size, void* d_ws, size_t ws_size,
                              hipStream_t stream)
{
    const float* xyz   = (const float*)d_in[0];
    const float* dirv  = (const float*)d_in[1];
    const float* table = (const float*)d_in[2];
    const float* ws1   = (const float*)d_in[3];
    const float* ws2   = (const float*)d_in[4];
    const float* wr1   = (const float*)d_in[5];
    const float* wr2   = (const float*)d_in[6];
    const float* wr3   = (const float*)d_in[7];
    float* out = (float*)d_out;

    const int n = in_sizes[0] / 3;
    dim3 block(256), grid((n + 255) / 256);

    const size_t enc_bytes = (size_t)n * 16 * sizeof(float2);   // 268 MB at n=2^21
    if (ws_size >= enc_bytes) {
        float2* ws_enc = (float2*)d_ws;
        hipLaunchKernelGGL(encode_kernel, grid, block, 0, stream, xyz, table, ws_enc, n);
        hipLaunchKernelGGL(mlp_kernel, grid, block, 0, stream,
                           ws_enc, dirv, ws1, ws2, wr1, wr2, wr3, out, n);
    } else {
        hipLaunchKernelGGL(nerf_fused, grid, block, 0, stream,
                           xyz, dirv, table, ws1, ws2, wr1, wr2, wr3, out, n);
    }
}

// Round 5
// 1475.728 us; speedup vs baseline: 1.4132x; 1.4132x over previous
//
#include <hip/hip_runtime.h>
#include <hip/hip_bf16.h>
#include <cmath>

#define TBL (1 << 19)   // T = 2^19 hash table entries per level (power of two)

__device__ __forceinline__ float relu_f(float x) { return fmaxf(x, 0.0f); }

// res_l = floor(16 * 1.3819^l); dense iff (res+1)^3 <= 2^19  (l = 0..4)
#define RES_LIST {16, 22, 30, 42, 58, 80, 111, 153, 212, 294, 406, 561, 775, 1072, 1481, 2047}

// ---------------------------------------------------------------------------
// XCD-pinned encode. One block = 256 points of ONE level. level chosen from
// blockIdx%8 via a packed nibble table so all blocks of a level land on one
// XCD (round-robin blockIdx%8 -> XCD heuristic). Each hashed level's table is
// exactly 4 MB == one XCD's L2, so after pinning the gathers are L2-hits.
// xyz reads and enc writes are nontemporal so the streaming traffic doesn't
// evict the resident table.
// Two passes (11 hashed levels > 8 XCDs):
//   pass A: levels 5..12   packed 0xCBA98765
//   pass B: levels 13,14,15,0,1,2,3,4  packed 0x43210FED
// ---------------------------------------------------------------------------
__global__ __launch_bounds__(256, 8)
void encode_pinned(const float* __restrict__ xyz,
                   const float* __restrict__ table,
                   float* __restrict__ ws_enc,      // float2 slots [level*n + i]
                   unsigned levels_packed,
                   int n)
{
    constexpr unsigned RES[16] = RES_LIST;

    const unsigned sub = blockIdx.x & 7u;
    const unsigned level = (levels_packed >> (4u * sub)) & 0xFu;
    const int i = (int)(blockIdx.x >> 3) * 256 + (int)threadIdx.x;
    if (i >= n) return;

    const float px_ = __builtin_nontemporal_load(xyz + 3 * (size_t)i + 0);
    const float py_ = __builtin_nontemporal_load(xyz + 3 * (size_t)i + 1);
    const float pz_ = __builtin_nontemporal_load(xyz + 3 * (size_t)i + 2);

    const unsigned res = RES[level];
    const float fr = (float)res;
    const float posx = px_ * fr, posy = py_ * fr, posz = pz_ * fr;
    const float fx = floorf(posx), fy = floorf(posy), fz = floorf(posz);
    const float wx = posx - fx, wy = posy - fy, wz = posz - fz;
    const unsigned x0 = (unsigned)fx, y0 = (unsigned)fy, z0 = (unsigned)fz;
    const float* tb = table + (size_t)level * (TBL * 2);

    float a0 = 0.0f, a1 = 0.0f;
    if (level < 5) {                      // dense (wave-uniform branch)
        const unsigned s = res + 1u;
        const unsigned s2 = s * s;
#pragma unroll
        for (int c = 0; c < 8; ++c) {
            const unsigned cx = x0 + (c & 1);
            const unsigned cy = y0 + ((c >> 1) & 1);
            const unsigned cz = z0 + ((c >> 2) & 1);
            const unsigned idx = cx + cy * s + cz * s2;
            const float w = ((c & 1) ? wx : 1.0f - wx) *
                            ((c & 2) ? wy : 1.0f - wy) *
                            ((c & 4) ? wz : 1.0f - wz);
            const float2 f = *reinterpret_cast<const float2*>(tb + 2u * idx);
            a0 = fmaf(f.x, w, a0);
            a1 = fmaf(f.y, w, a1);
        }
    } else {                              // hashed
#pragma unroll
        for (int c = 0; c < 8; ++c) {
            const unsigned cx = x0 + (c & 1);
            const unsigned cy = y0 + ((c >> 1) & 1);
            const unsigned cz = z0 + ((c >> 2) & 1);
            unsigned idx = (cx * 1u) ^ (cy * 2654435761u) ^ (cz * 805459861u);
            idx &= (unsigned)(TBL - 1);
            const float w = ((c & 1) ? wx : 1.0f - wx) *
                            ((c & 2) ? wy : 1.0f - wy) *
                            ((c & 4) ? wz : 1.0f - wz);
            const float2 f = *reinterpret_cast<const float2*>(tb + 2u * idx);
            a0 = fmaf(f.x, w, a0);
            a1 = fmaf(f.y, w, a1);
        }
    }

    float* dst = ws_enc + 2 * ((size_t)level * n + i);
    __builtin_nontemporal_store(a0, dst + 0);
    __builtin_nontemporal_store(a1, dst + 1);
}

// ---------------------------------------------------------------------------
// Kernel 2: the MLPs (unchanged from round 4). One thread per point; enc
// streamed from ws; activations held one array at a time. VALU-bound.
// ---------------------------------------------------------------------------
__global__ __launch_bounds__(256, 4)
void mlp_kernel(const float2* __restrict__ ws_enc,
                const float* __restrict__ dirv,
                const float* __restrict__ ws1,   // (32,64)
                const float* __restrict__ ws2,   // (64,17)
                const float* __restrict__ wr1,   // (32,64)
                const float* __restrict__ wr2,   // (64,64)
                const float* __restrict__ wr3,   // (64,3)
                float* __restrict__ out,
                int n)
{
    const int i = blockIdx.x * 256 + threadIdx.x;
    if (i >= n) return;

    // ---------------- sigma MLP: enc(32) -> 64 -> 17 ----------------
    float h[64];
#pragma unroll
    for (int j = 0; j < 64; ++j) h[j] = 0.0f;
#pragma unroll
    for (int l = 0; l < 16; ++l) {
        const float2 e = ws_enc[(size_t)l * n + i];
#pragma unroll
        for (int j = 0; j < 64; ++j) h[j] = fmaf(e.x, ws1[(2 * l) * 64 + j], h[j]);
#pragma unroll
        for (int j = 0; j < 64; ++j) h[j] = fmaf(e.y, ws1[(2 * l + 1) * 64 + j], h[j]);
    }
#pragma unroll
    for (int j = 0; j < 64; ++j) h[j] = relu_f(h[j]);

    float geo[17];
#pragma unroll
    for (int j = 0; j < 17; ++j) geo[j] = 0.0f;
#pragma unroll
    for (int k = 0; k < 64; ++k) {
        const float e = h[k];
#pragma unroll
        for (int j = 0; j < 17; ++j) geo[j] = fmaf(e, ws2[k * 17 + j], geo[j]);
    }
    out[3 * (size_t)n + (size_t)i] = relu_f(geo[0]);
    // h[] dead from here

    // ---------------- SH deg-4 of dir*2-1 ----------------
    const float dx = dirv[3 * (size_t)i + 0] * 2.0f - 1.0f;
    const float dy = dirv[3 * (size_t)i + 1] * 2.0f - 1.0f;
    const float dz = dirv[3 * (size_t)i + 2] * 2.0f - 1.0f;
    const float x2 = dx * dx, y2 = dy * dy, z2 = dz * dz;
    const float xy = dx * dy, yz = dy * dz, xz = dx * dz;

    float sh[16];
    sh[0]  = 0.28209479177387814f;
    sh[1]  = -0.48860251190291987f * dy;
    sh[2]  = 0.48860251190291987f * dz;
    sh[3]  = -0.48860251190291987f * dx;
    sh[4]  = 1.0925484305920792f * xy;
    sh[5]  = -1.0925484305920792f * yz;
    sh[6]  = 0.94617469575756f * z2 - 0.31539156525252f;
    sh[7]  = -1.0925484305920792f * xz;
    sh[8]  = 0.5462742152960396f * (x2 - y2);
    sh[9]  = 0.5900435899266435f * dy * (-3.0f * x2 + y2);
    sh[10] = 2.890611442640554f * xy * dz;
    sh[11] = 0.4570457994644657f * dy * (1.0f - 5.0f * z2);
    sh[12] = 0.3731763325901154f * dz * (5.0f * z2 - 3.0f);
    sh[13] = 0.4570457994644657f * dx * (1.0f - 5.0f * z2);
    sh[14] = 1.445305721320277f * dz * (x2 - y2);
    sh[15] = 0.5900435899266435f * dx * (-x2 + 3.0f * y2);

    // ---------------- rgb MLP: [sh(16) | geo[1..17](16)] -> 64 -> 64 -> 3 ----
    float g[64];
#pragma unroll
    for (int j = 0; j < 64; ++j) g[j] = 0.0f;
#pragma unroll
    for (int k = 0; k < 16; ++k) {
        const float e = sh[k];
#pragma unroll
        for (int j = 0; j < 64; ++j) g[j] = fmaf(e, wr1[k * 64 + j], g[j]);
    }
#pragma unroll
    for (int k = 16; k < 32; ++k) {
        const float e = geo[k - 15];   // geo_feat[k-16] = geo[k-16+1]
#pragma unroll
        for (int j = 0; j < 64; ++j) g[j] = fmaf(e, wr1[k * 64 + j], g[j]);
    }
#pragma unroll
    for (int j = 0; j < 64; ++j) g[j] = relu_f(g[j]);
    // sh[], geo[] dead from here

    // rgb layer 2 in two 32-neuron halves to cap live registers at ~g[64]+32
    float r0 = 0.0f, r1 = 0.0f, r2 = 0.0f;
#pragma unroll
    for (int half = 0; half < 2; ++half) {
        const int j0 = half * 32;
        float g2h[32];
#pragma unroll
        for (int j = 0; j < 32; ++j) g2h[j] = 0.0f;
#pragma unroll
        for (int k = 0; k < 64; ++k) {
            const float e = g[k];
#pragma unroll
            for (int j = 0; j < 32; ++j) g2h[j] = fmaf(e, wr2[k * 64 + j0 + j], g2h[j]);
        }
#pragma unroll
        for (int j = 0; j < 32; ++j) {
            const float e = relu_f(g2h[j]);
            r0 = fmaf(e, wr3[(j0 + j) * 3 + 0], r0);
            r1 = fmaf(e, wr3[(j0 + j) * 3 + 1], r1);
            r2 = fmaf(e, wr3[(j0 + j) * 3 + 2], r2);
        }
    }

    out[3 * (size_t)i + 0] = 1.0f / (1.0f + __expf(-r0));
    out[3 * (size_t)i + 1] = 1.0f / (1.0f + __expf(-r1));
    out[3 * (size_t)i + 2] = 1.0f / (1.0f + __expf(-r2));
}

// ---------------------------------------------------------------------------
// Fallback: round-3 fused kernel (used only if ws_size can't hold enc).
// ---------------------------------------------------------------------------
__global__ __launch_bounds__(256, 4)
void nerf_fused(const float* __restrict__ xyz,
                const float* __restrict__ dirv,
                const float* __restrict__ table,
                const float* __restrict__ ws1,
                const float* __restrict__ ws2,
                const float* __restrict__ wr1,
                const float* __restrict__ wr2,
                const float* __restrict__ wr3,
                float* __restrict__ out,
                int n)
{
    constexpr unsigned RES[16] = RES_LIST;

    const int i = blockIdx.x * 256 + threadIdx.x;
    if (i >= n) return;

    const float px_ = xyz[3 * (size_t)i + 0];
    const float py_ = xyz[3 * (size_t)i + 1];
    const float pz_ = xyz[3 * (size_t)i + 2];

    float enc[32];
#pragma unroll
    for (int l = 0; l < 16; ++l) {
        const unsigned res = RES[l];
        const float fr = (float)res;
        const float posx = px_ * fr, posy = py_ * fr, posz = pz_ * fr;
        const float fx = floorf(posx), fy = floorf(posy), fz = floorf(posz);
        const float wx = posx - fx, wy = posy - fy, wz = posz - fz;
        const unsigned x0 = (unsigned)fx, y0 = (unsigned)fy, z0 = (unsigned)fz;
        const float* tb = table + (size_t)l * (TBL * 2);
        float a0 = 0.0f, a1 = 0.0f;
#pragma unroll
        for (int c = 0; c < 8; ++c) {
            const unsigned cx = x0 + (c & 1);
            const unsigned cy = y0 + ((c >> 1) & 1);
            const unsigned cz = z0 + ((c >> 2) & 1);
            unsigned idx;
            if (l < 5) {
                const unsigned s = res + 1u;
                idx = cx + cy * s + cz * (s * s);
            } else {
                idx = (cx * 1u) ^ (cy * 2654435761u) ^ (cz * 805459861u);
                idx &= (unsigned)(TBL - 1);
            }
            const float w = ((c & 1) ? wx : 1.0f - wx) *
                            ((c & 2) ? wy : 1.0f - wy) *
                            ((c & 4) ? wz : 1.0f - wz);
            const float2 f = *reinterpret_cast<const float2*>(tb + 2u * idx);
            a0 = fmaf(f.x, w, a0);
            a1 = fmaf(f.y, w, a1);
        }
        enc[2 * l + 0] = a0;
        enc[2 * l + 1] = a1;
    }

    float h[64];
#pragma unroll
    for (int j = 0; j < 64; ++j) h[j] = 0.0f;
#pragma unroll
    for (int k = 0; k < 32; ++k) {
        const float e = enc[k];
#pragma unroll
        for (int j = 0; j < 64; ++j) h[j] = fmaf(e, ws1[k * 64 + j], h[j]);
    }
#pragma unroll
    for (int j = 0; j < 64; ++j) h[j] = relu_f(h[j]);

    float geo[17];
#pragma unroll
    for (int j = 0; j < 17; ++j) geo[j] = 0.0f;
#pragma unroll
    for (int k = 0; k < 64; ++k) {
        const float e = h[k];
#pragma unroll
        for (int j = 0; j < 17; ++j) geo[j] = fmaf(e, ws2[k * 17 + j], geo[j]);
    }
    out[3 * (size_t)n + (size_t)i] = relu_f(geo[0]);

    const float dx = dirv[3 * (size_t)i + 0] * 2.0f - 1.0f;
    const float dy = dirv[3 * (size_t)i + 1] * 2.0f - 1.0f;
    const float dz = dirv[3 * (size_t)i + 2] * 2.0f - 1.0f;
    const float x2 = dx * dx, y2 = dy * dy, z2 = dz * dz;
    const float xy = dx * dy, yz = dy * dz, xz = dx * dz;

    float sh[16];
    sh[0]  = 0.28209479177387814f;
    sh[1]  = -0.48860251190291987f * dy;
    sh[2]  = 0.48860251190291987f * dz;
    sh[3]  = -0.48860251190291987f * dx;
    sh[4]  = 1.0925484305920792f * xy;
    sh[5]  = -1.0925484305920792f * yz;
    sh[6]  = 0.94617469575756f * z2 - 0.31539156525252f;
    sh[7]  = -1.0925484305920792f * xz;
    sh[8]  = 0.5462742152960396f * (x2 - y2);
    sh[9]  = 0.5900435899266435f * dy * (-3.0f * x2 + y2);
    sh[10] = 2.890611442640554f * xy * dz;
    sh[11] = 0.4570457994644657f * dy * (1.0f - 5.0f * z2);
    sh[12] = 0.3731763325901154f * dz * (5.0f * z2 - 3.0f);
    sh[13] = 0.4570457994644657f * dx * (1.0f - 5.0f * z2);
    sh[14] = 1.445305721320277f * dz * (x2 - y2);
    sh[15] = 0.5900435899266435f * dx * (-x2 + 3.0f * y2);

    float g[64];
#pragma unroll
    for (int j = 0; j < 64; ++j) g[j] = 0.0f;
#pragma unroll
    for (int k = 0; k < 16; ++k) {
        const float e = sh[k];
#pragma unroll
        for (int j = 0; j < 64; ++j) g[j] = fmaf(e, wr1[k * 64 + j], g[j]);
    }
#pragma unroll
    for (int k = 16; k < 32; ++k) {
        const float e = geo[k - 15];
#pragma unroll
        for (int j = 0; j < 64; ++j) g[j] = fmaf(e, wr1[k * 64 + j], g[j]);
    }
#pragma unroll
    for (int j = 0; j < 64; ++j) g[j] = relu_f(g[j]);

    float r0 = 0.0f, r1 = 0.0f, r2 = 0.0f;
#pragma unroll
    for (int half = 0; half < 2; ++half) {
        const int j0 = half * 32;
        float g2h[32];
#pragma unroll
        for (int j = 0; j < 32; ++j) g2h[j] = 0.0f;
#pragma unroll
        for (int k = 0; k < 64; ++k) {
            const float e = g[k];
#pragma unroll
            for (int j = 0; j < 32; ++j) g2h[j] = fmaf(e, wr2[k * 64 + j0 + j], g2h[j]);
        }
#pragma unroll
        for (int j = 0; j < 32; ++j) {
            const float e = relu_f(g2h[j]);
            r0 = fmaf(e, wr3[(j0 + j) * 3 + 0], r0);
            r1 = fmaf(e, wr3[(j0 + j) * 3 + 1], r1);
            r2 = fmaf(e, wr3[(j0 + j) * 3 + 2], r2);
        }
    }

    out[3 * (size_t)i + 0] = 1.0f / (1.0f + __expf(-r0));
    out[3 * (size_t)i + 1] = 1.0f / (1.0f + __expf(-r1));
    out[3 * (size_t)i + 2] = 1.0f / (1.0f + __expf(-r2));
}

extern "C" void kernel_launch(void* const* d_in, const int* in_sizes, int n_in,
                              void* d_out, int out_size, void* d_ws, size_t ws_size,
                              hipStream_t stream)
{
    const float* xyz   = (const float*)d_in[0];
    const float* dirv  = (const float*)d_in[1];
    const float* table = (const float*)d_in[2];
    const float* ws1   = (const float*)d_in[3];
    const float* ws2   = (const float*)d_in[4];
    const float* wr1   = (const float*)d_in[5];
    const float* wr2   = (const float*)d_in[6];
    const float* wr3   = (const float*)d_in[7];
    float* out = (float*)d_out;

    const int n = in_sizes[0] / 3;
    const int blocks_per_level = (n + 255) / 256;
    dim3 block(256);
    dim3 grid_mlp(blocks_per_level);
    dim3 grid_enc(8 * blocks_per_level);

    const size_t enc_bytes = (size_t)n * 16 * sizeof(float2);   // 268 MB at n=2^21
    if (ws_size >= enc_bytes) {
        float* ws_enc = (float*)d_ws;
        // pass A: hashed levels 5..12, one per XCD (4 MB table == 4 MB L2)
        hipLaunchKernelGGL(encode_pinned, grid_enc, block, 0, stream,
                           xyz, table, ws_enc, 0xCBA98765u, n);
        // pass B: levels 13,14,15 on XCDs 0..2; dense 0..4 on XCDs 3..7
        hipLaunchKernelGGL(encode_pinned, grid_enc, block, 0, stream,
                           xyz, table, ws_enc, 0x43210FEDu, n);
        hipLaunchKernelGGL(mlp_kernel, grid_mlp, block, 0, stream,
                           (const float2*)ws_enc, dirv, ws1, ws2, wr1, wr2, wr3, out, n);
    } else {
        hipLaunchKernelGGL(nerf_fused, grid_mlp, block, 0, stream,
                           xyz, dirv, table, ws1, ws2, wr1, wr2, wr3, out, n);
    }
}

// Round 6
// 1107.924 us; speedup vs baseline: 1.8823x; 1.3320x over previous
//
#include <hip/hip_runtime.h>
#include <hip/hip_bf16.h>
#include <cmath>

#define TBL (1 << 19)   // T = 2^19 hash table entries per level (power of two)

__device__ __forceinline__ float relu_f(float x) { return fmaxf(x, 0.0f); }

// fp32 -> bf16 bits, round-to-nearest-even
__device__ __forceinline__ unsigned short f2bf(float x) {
    union { float f; unsigned u; } v; v.f = x;
    const unsigned r = v.u + 0x7FFFu + ((v.u >> 16) & 1u);
    return (unsigned short)(r >> 16);
}

typedef __attribute__((ext_vector_type(8))) short short8;   // 8 bf16 = 4 VGPRs (A/B frag)
typedef __attribute__((ext_vector_type(4))) float floatx4;  // C/D frag

// res_l = floor(16 * 1.3819^l); dense iff (res+1)^3 <= 2^19  (l = 0..4)
#define RES_LIST {16, 22, 30, 42, 58, 80, 111, 153, 212, 294, 406, 561, 775, 1072, 1481, 2047}

// ---------------------------------------------------------------------------
// XCD-pinned encode (unchanged from round 5): blockIdx%8 selects a level via
// packed nibbles so each hashed level's 4 MB table stays resident in one
// XCD's 4 MB L2. Nontemporal xyz/enc streaming to avoid evicting the table.
// ---------------------------------------------------------------------------
__global__ __launch_bounds__(256, 8)
void encode_pinned(const float* __restrict__ xyz,
                   const float* __restrict__ table,
                   float* __restrict__ ws_enc,      // float2 slots [level*n + i]
                   unsigned levels_packed,
                   int n)
{
    constexpr unsigned RES[16] = RES_LIST;

    const unsigned sub = blockIdx.x & 7u;
    const unsigned level = (levels_packed >> (4u * sub)) & 0xFu;
    const int i = (int)(blockIdx.x >> 3) * 256 + (int)threadIdx.x;
    if (i >= n) return;

    const float px_ = __builtin_nontemporal_load(xyz + 3 * (size_t)i + 0);
    const float py_ = __builtin_nontemporal_load(xyz + 3 * (size_t)i + 1);
    const float pz_ = __builtin_nontemporal_load(xyz + 3 * (size_t)i + 2);

    const unsigned res = RES[level];
    const float fr = (float)res;
    const float posx = px_ * fr, posy = py_ * fr, posz = pz_ * fr;
    const float fx = floorf(posx), fy = floorf(posy), fz = floorf(posz);
    const float wx = posx - fx, wy = posy - fy, wz = posz - fz;
    const unsigned x0 = (unsigned)fx, y0 = (unsigned)fy, z0 = (unsigned)fz;
    const float* tb = table + (size_t)level * (TBL * 2);

    float a0 = 0.0f, a1 = 0.0f;
    if (level < 5) {
        const unsigned s = res + 1u;
        const unsigned s2 = s * s;
#pragma unroll
        for (int c = 0; c < 8; ++c) {
            const unsigned cx = x0 + (c & 1);
            const unsigned cy = y0 + ((c >> 1) & 1);
            const unsigned cz = z0 + ((c >> 2) & 1);
            const unsigned idx = cx + cy * s + cz * s2;
            const float w = ((c & 1) ? wx : 1.0f - wx) *
                            ((c & 2) ? wy : 1.0f - wy) *
                            ((c & 4) ? wz : 1.0f - wz);
            const float2 f = *reinterpret_cast<const float2*>(tb + 2u * idx);
            a0 = fmaf(f.x, w, a0);
            a1 = fmaf(f.y, w, a1);
        }
    } else {
#pragma unroll
        for (int c = 0; c < 8; ++c) {
            const unsigned cx = x0 + (c & 1);
            const unsigned cy = y0 + ((c >> 1) & 1);
            const unsigned cz = z0 + ((c >> 2) & 1);
            unsigned idx = (cx * 1u) ^ (cy * 2654435761u) ^ (cz * 805459861u);
            idx &= (unsigned)(TBL - 1);
            const float w = ((c & 1) ? wx : 1.0f - wx) *
                            ((c & 2) ? wy : 1.0f - wy) *
                            ((c & 4) ? wz : 1.0f - wz);
            const float2 f = *reinterpret_cast<const float2*>(tb + 2u * idx);
            a0 = fmaf(f.x, w, a0);
            a1 = fmaf(f.y, w, a1);
        }
    }

    float* dst = ws_enc + 2 * ((size_t)level * n + i);
    __builtin_nontemporal_store(a0, dst + 0);
    __builtin_nontemporal_store(a1, dst + 1);
}

// ---------------------------------------------------------------------------
// MFMA MLP. Block = 256 thr = 4 waves; wave owns 64 points = 4 M-tiles of 16.
// v_mfma_f32_16x16x32_bf16 layouts (HW-verified, learn_hip m89/m91/m120):
//   A: m = lane&15, k = (lane>>4)*8 + j   (j = vector elem 0..7)
//   B: n = lane&15, k = (lane>>4)*8 + j
//   D: col(n) = lane&15, row(m) = (lane>>4)*4 + reg
// Weights staged once/block to LDS, bf16, TRANSPOSED [n][k] so a B-frag is
// one 16 B ds_read. Pitches 40 elems (K=32) / 72 elems (K=64): 80/144 B rows
// keep 16 B alignment; mr vs mr+8 share banks = free 2-way conflict (m136).
// Activations round-trip per-wave LDS buffers for the D->A transform.
// ws2 padded to N=32, wr3 to N=16 with zeros.
// ---------------------------------------------------------------------------
__global__ __launch_bounds__(256)
void mlp_mfma(const float* __restrict__ ws_enc,
              const float* __restrict__ dirv,
              const float* __restrict__ ws1,   // (32,64)
              const float* __restrict__ ws2,   // (64,17)
              const float* __restrict__ wr1,   // (32,64)
              const float* __restrict__ wr2,   // (64,64)
              const float* __restrict__ wr3,   // (64,3)
              float* __restrict__ out,
              int n)
{
    // LDS weight offsets (shorts):  ws1 @0 (64*40)  ws2 @2560 (32*72)
    // wr1 @4864 (64*40)  wr2 @7424 (64*72)  wr3 @12032 (16*72)  total 13184
    __shared__ alignas(16) unsigned short s_w[13184];
    __shared__ alignas(16) unsigned short s_act[4 * 16 * 72];  // per-wave h/g/g2
    __shared__ alignas(16) float          s_geo[4 * 16 * 20];  // per-wave geo fp32

    const int tid = threadIdx.x;

    for (int e = tid; e < 13184; e += 256) s_w[e] = 0;
    __syncthreads();
    for (int e = tid; e < 2048; e += 256) { const int k = e >> 6, j = e & 63; s_w[0     + j * 40 + k] = f2bf(ws1[e]); }
    for (int e = tid; e < 1088; e += 256) { const int k = e / 17, j = e % 17; s_w[2560  + j * 72 + k] = f2bf(ws2[e]); }
    for (int e = tid; e < 2048; e += 256) { const int k = e >> 6, j = e & 63; s_w[4864  + j * 40 + k] = f2bf(wr1[e]); }
    for (int e = tid; e < 4096; e += 256) { const int k = e >> 6, j = e & 63; s_w[7424  + j * 72 + k] = f2bf(wr2[e]); }
    for (int e = tid; e < 192;  e += 256) { const int k = e / 3,  j = e % 3;  s_w[12032 + j * 72 + k] = f2bf(wr3[e]); }
    __syncthreads();

    const int wave = tid >> 6;
    const int lane = tid & 63;
    const int q    = lane >> 4;    // quad 0..3
    const int mr   = lane & 15;    // row/col-within-16
    unsigned short* hb = s_act + wave * (16 * 72);
    float*          gb = s_geo + wave * (16 * 20);
    const int base = blockIdx.x * 256 + wave * 64;
    if (base >= n) return;

#pragma unroll 1
    for (int mt = 0; mt < 4; ++mt) {
        const int pt = base + mt * 16 + mr;

        // ---- enc A-fragment straight from global (k = q*8+j -> level q*4+j/2, comp j&1)
        short8 aenc;
#pragma unroll
        for (int t = 0; t < 4; ++t) {
            const float2 e = *reinterpret_cast<const float2*>(ws_enc + 2 * ((size_t)(q * 4 + t) * n + pt));
            aenc[2 * t + 0] = (short)f2bf(e.x);
            aenc[2 * t + 1] = (short)f2bf(e.y);
        }

        // ---- sigma L1: enc(32) -> h(64), 4 N-chunks
#pragma unroll
        for (int nc = 0; nc < 4; ++nc) {
            const short8 b = *reinterpret_cast<const short8*>(s_w + 0 + (nc * 16 + mr) * 40 + q * 8);
            floatx4 acc = {0.f, 0.f, 0.f, 0.f};
            acc = __builtin_amdgcn_mfma_f32_16x16x32_bf16(aenc, b, acc, 0, 0, 0);
#pragma unroll
            for (int r = 0; r < 4; ++r)
                hb[(q * 4 + r) * 72 + nc * 16 + mr] = f2bf(fmaxf(acc[r], 0.f));
        }
        __builtin_amdgcn_wave_barrier();

        // ---- sigma L2: h(64) -> geo(17, padded 32), K=64 in 2 steps
        {
            const short8 a0 = *reinterpret_cast<const short8*>(hb + mr * 72 + 0  + q * 8);
            const short8 a1 = *reinterpret_cast<const short8*>(hb + mr * 72 + 32 + q * 8);
            floatx4 acc0 = {0.f, 0.f, 0.f, 0.f};
            floatx4 acc1 = {0.f, 0.f, 0.f, 0.f};
            {
                const short8 b0 = *reinterpret_cast<const short8*>(s_w + 2560 + mr * 72 + 0  + q * 8);
                const short8 b1 = *reinterpret_cast<const short8*>(s_w + 2560 + mr * 72 + 32 + q * 8);
                acc0 = __builtin_amdgcn_mfma_f32_16x16x32_bf16(a0, b0, acc0, 0, 0, 0);
                acc0 = __builtin_amdgcn_mfma_f32_16x16x32_bf16(a1, b1, acc0, 0, 0, 0);
            }
            {
                const short8 b0 = *reinterpret_cast<const short8*>(s_w + 2560 + (16 + mr) * 72 + 0  + q * 8);
                const short8 b1 = *reinterpret_cast<const short8*>(s_w + 2560 + (16 + mr) * 72 + 32 + q * 8);
                acc1 = __builtin_amdgcn_mfma_f32_16x16x32_bf16(a0, b0, acc1, 0, 0, 0);
                acc1 = __builtin_amdgcn_mfma_f32_16x16x32_bf16(a1, b1, acc1, 0, 0, 0);
            }
            // geometry col c stored at LDS col c+3 (keeps geo[1] 16 B-aligned)
#pragma unroll
            for (int r = 0; r < 4; ++r) gb[(q * 4 + r) * 20 + mr + 3] = acc0[r];
            if (mr == 0) {
#pragma unroll
                for (int r = 0; r < 4; ++r) gb[(q * 4 + r) * 20 + 19] = acc1[r];
            }
        }
        __builtin_amdgcn_wave_barrier();

        // ---- sigma output (lanes 0..15, coalesced 64 B)
        if (lane < 16)
            out[3 * (size_t)n + (size_t)(base + mt * 16 + lane)] = fmaxf(gb[lane * 20 + 3], 0.f);

        // ---- SH deg-4 for this point
        const float dx = dirv[3 * (size_t)pt + 0] * 2.0f - 1.0f;
        const float dy = dirv[3 * (size_t)pt + 1] * 2.0f - 1.0f;
        const float dz = dirv[3 * (size_t)pt + 2] * 2.0f - 1.0f;
        const float x2 = dx * dx, y2 = dy * dy, z2 = dz * dz;
        const float xy = dx * dy, yz = dy * dz, xz = dx * dz;
        float sh[16];
        sh[0]  = 0.28209479177387814f;
        sh[1]  = -0.48860251190291987f * dy;
        sh[2]  = 0.48860251190291987f * dz;
        sh[3]  = -0.48860251190291987f * dx;
        sh[4]  = 1.0925484305920792f * xy;
        sh[5]  = -1.0925484305920792f * yz;
        sh[6]  = 0.94617469575756f * z2 - 0.31539156525252f;
        sh[7]  = -1.0925484305920792f * xz;
        sh[8]  = 0.5462742152960396f * (x2 - y2);
        sh[9]  = 0.5900435899266435f * dy * (-3.0f * x2 + y2);
        sh[10] = 2.890611442640554f * xy * dz;
        sh[11] = 0.4570457994644657f * dy * (1.0f - 5.0f * z2);
        sh[12] = 0.3731763325901154f * dz * (5.0f * z2 - 3.0f);
        sh[13] = 0.4570457994644657f * dx * (1.0f - 5.0f * z2);
        sh[14] = 1.445305721320277f * dz * (x2 - y2);
        sh[15] = 0.5900435899266435f * dx * (-x2 + 3.0f * y2);

        // ---- rgb L1 A-frag: k<16 -> sh[k]; k>=16 -> geometry[k-15] from LDS
        short8 ar;
        if (q < 2) {
#pragma unroll
            for (int j = 0; j < 8; ++j) ar[j] = (short)f2bf(sh[q * 8 + j]);
        } else {
            // geometry cols (q-2)*8+1 .. +8  -> LDS cols 4..11 / 12..19
            const floatx4 g0 = *reinterpret_cast<const floatx4*>(gb + mr * 20 + 4 + (q - 2) * 8);
            const floatx4 g1 = *reinterpret_cast<const floatx4*>(gb + mr * 20 + 8 + (q - 2) * 8);
#pragma unroll
            for (int j = 0; j < 4; ++j) { ar[j] = (short)f2bf(g0[j]); ar[4 + j] = (short)f2bf(g1[j]); }
        }

        // ---- rgb L1: rin(32) -> g(64)   (overwrites h in hb; h already consumed)
#pragma unroll
        for (int nc = 0; nc < 4; ++nc) {
            const short8 b = *reinterpret_cast<const short8*>(s_w + 4864 + (nc * 16 + mr) * 40 + q * 8);
            floatx4 acc = {0.f, 0.f, 0.f, 0.f};
            acc = __builtin_amdgcn_mfma_f32_16x16x32_bf16(ar, b, acc, 0, 0, 0);
#pragma unroll
            for (int r = 0; r < 4; ++r)
                hb[(q * 4 + r) * 72 + nc * 16 + mr] = f2bf(fmaxf(acc[r], 0.f));
        }
        __builtin_amdgcn_wave_barrier();

        // ---- rgb L2: g(64) -> g2(64)  (read A-frags first, then overwrite in place)
        {
            const short8 a0 = *reinterpret_cast<const short8*>(hb + mr * 72 + 0  + q * 8);
            const short8 a1 = *reinterpret_cast<const short8*>(hb + mr * 72 + 32 + q * 8);
            __builtin_amdgcn_wave_barrier();
#pragma unroll
            for (int nc = 0; nc < 4; ++nc) {
                const short8 b0 = *reinterpret_cast<const short8*>(s_w + 7424 + (nc * 16 + mr) * 72 + 0  + q * 8);
                const short8 b1 = *reinterpret_cast<const short8*>(s_w + 7424 + (nc * 16 + mr) * 72 + 32 + q * 8);
                floatx4 acc = {0.f, 0.f, 0.f, 0.f};
                acc = __builtin_amdgcn_mfma_f32_16x16x32_bf16(a0, b0, acc, 0, 0, 0);
                acc = __builtin_amdgcn_mfma_f32_16x16x32_bf16(a1, b1, acc, 0, 0, 0);
#pragma unroll
                for (int r = 0; r < 4; ++r)
                    hb[(q * 4 + r) * 72 + nc * 16 + mr] = f2bf(fmaxf(acc[r], 0.f));
            }
        }
        __builtin_amdgcn_wave_barrier();

        // ---- rgb L3: g2(64) -> rgb(3, padded 16)
        {
            const short8 a0 = *reinterpret_cast<const short8*>(hb + mr * 72 + 0  + q * 8);
            const short8 a1 = *reinterpret_cast<const short8*>(hb + mr * 72 + 32 + q * 8);
            const short8 b0 = *reinterpret_cast<const short8*>(s_w + 12032 + mr * 72 + 0  + q * 8);
            const short8 b1 = *reinterpret_cast<const short8*>(s_w + 12032 + mr * 72 + 32 + q * 8);
            floatx4 acc = {0.f, 0.f, 0.f, 0.f};
            acc = __builtin_amdgcn_mfma_f32_16x16x32_bf16(a0, b0, acc, 0, 0, 0);
            acc = __builtin_amdgcn_mfma_f32_16x16x32_bf16(a1, b1, acc, 0, 0, 0);
            if (mr < 3) {
#pragma unroll
                for (int r = 0; r < 4; ++r) {
                    const int p = base + mt * 16 + q * 4 + r;
                    out[3 * (size_t)p + mr] = 1.0f / (1.0f + __expf(-acc[r]));
                }
            }
        }
        __builtin_amdgcn_wave_barrier();
    }
}

// ---------------------------------------------------------------------------
// Fallback: round-3 fused kernel (used only if ws can't hold enc or n%256).
// ---------------------------------------------------------------------------
__global__ __launch_bounds__(256, 4)
void nerf_fused(const float* __restrict__ xyz,
                const float* __restrict__ dirv,
                const float* __restrict__ table,
                const float* __restrict__ ws1,
                const float* __restrict__ ws2,
                const float* __restrict__ wr1,
                const float* __restrict__ wr2,
                const float* __restrict__ wr3,
                float* __restrict__ out,
                int n)
{
    constexpr unsigned RES[16] = RES_LIST;

    const int i = blockIdx.x * 256 + threadIdx.x;
    if (i >= n) return;

    const float px_ = xyz[3 * (size_t)i + 0];
    const float py_ = xyz[3 * (size_t)i + 1];
    const float pz_ = xyz[3 * (size_t)i + 2];

    float enc[32];
#pragma unroll
    for (int l = 0; l < 16; ++l) {
        const unsigned res = RES[l];
        const float fr = (float)res;
        const float posx = px_ * fr, posy = py_ * fr, posz = pz_ * fr;
        const float fx = floorf(posx), fy = floorf(posy), fz = floorf(posz);
        const float wx = posx - fx, wy = posy - fy, wz = posz - fz;
        const unsigned x0 = (unsigned)fx, y0 = (unsigned)fy, z0 = (unsigned)fz;
        const float* tb = table + (size_t)l * (TBL * 2);
        float a0 = 0.0f, a1 = 0.0f;
#pragma unroll
        for (int c = 0; c < 8; ++c) {
            const unsigned cx = x0 + (c & 1);
            const unsigned cy = y0 + ((c >> 1) & 1);
            const unsigned cz = z0 + ((c >> 2) & 1);
            unsigned idx;
            if (l < 5) {
                const unsigned s = res + 1u;
                idx = cx + cy * s + cz * (s * s);
            } else {
                idx = (cx * 1u) ^ (cy * 2654435761u) ^ (cz * 805459861u);
                idx &= (unsigned)(TBL - 1);
            }
            const float w = ((c & 1) ? wx : 1.0f - wx) *
                            ((c & 2) ? wy : 1.0f - wy) *
                            ((c & 4) ? wz : 1.0f - wz);
            const float2 f = *reinterpret_cast<const float2*>(tb + 2u * idx);
            a0 = fmaf(f.x, w, a0);
            a1 = fmaf(f.y, w, a1);
        }
        enc[2 * l + 0] = a0;
        enc[2 * l + 1] = a1;
    }

    float h[64];
#pragma unroll
    for (int j = 0; j < 64; ++j) h[j] = 0.0f;
#pragma unroll
    for (int k = 0; k < 32; ++k) {
        const float e = enc[k];
#pragma unroll
        for (int j = 0; j < 64; ++j) h[j] = fmaf(e, ws1[k * 64 + j], h[j]);
    }
#pragma unroll
    for (int j = 0; j < 64; ++j) h[j] = relu_f(h[j]);

    float geo[17];
#pragma unroll
    for (int j = 0; j < 17; ++j) geo[j] = 0.0f;
#pragma unroll
    for (int k = 0; k < 64; ++k) {
        const float e = h[k];
#pragma unroll
        for (int j = 0; j < 17; ++j) geo[j] = fmaf(e, ws2[k * 17 + j], geo[j]);
    }
    out[3 * (size_t)n + (size_t)i] = relu_f(geo[0]);

    const float dx = dirv[3 * (size_t)i + 0] * 2.0f - 1.0f;
    const float dy = dirv[3 * (size_t)i + 1] * 2.0f - 1.0f;
    const float dz = dirv[3 * (size_t)i + 2] * 2.0f - 1.0f;
    const float x2 = dx * dx, y2 = dy * dy, z2 = dz * dz;
    const float xy = dx * dy, yz = dy * dz, xz = dx * dz;

    float sh[16];
    sh[0]  = 0.28209479177387814f;
    sh[1]  = -0.48860251190291987f * dy;
    sh[2]  = 0.48860251190291987f * dz;
    sh[3]  = -0.48860251190291987f * dx;
    sh[4]  = 1.0925484305920792f * xy;
    sh[5]  = -1.0925484305920792f * yz;
    sh[6]  = 0.94617469575756f * z2 - 0.31539156525252f;
    sh[7]  = -1.0925484305920792f * xz;
    sh[8]  = 0.5462742152960396f * (x2 - y2);
    sh[9]  = 0.5900435899266435f * dy * (-3.0f * x2 + y2);
    sh[10] = 2.890611442640554f * xy * dz;
    sh[11] = 0.4570457994644657f * dy * (1.0f - 5.0f * z2);
    sh[12] = 0.3731763325901154f * dz * (5.0f * z2 - 3.0f);
    sh[13] = 0.4570457994644657f * dx * (1.0f - 5.0f * z2);
    sh[14] = 1.445305721320277f * dz * (x2 - y2);
    sh[15] = 0.5900435899266435f * dx * (-x2 + 3.0f * y2);

    float g[64];
#pragma unroll
    for (int j = 0; j < 64; ++j) g[j] = 0.0f;
#pragma unroll
    for (int k = 0; k < 16; ++k) {
        const float e = sh[k];
#pragma unroll
        for (int j = 0; j < 64; ++j) g[j] = fmaf(e, wr1[k * 64 + j], g[j]);
    }
#pragma unroll
    for (int k = 16; k < 32; ++k) {
        const float e = geo[k - 15];
#pragma unroll
        for (int j = 0; j < 64; ++j) g[j] = fmaf(e, wr1[k * 64 + j], g[j]);
    }
#pragma unroll
    for (int j = 0; j < 64; ++j) g[j] = relu_f(g[j]);

    float r0 = 0.0f, r1 = 0.0f, r2 = 0.0f;
#pragma unroll
    for (int half = 0; half < 2; ++half) {
        const int j0 = half * 32;
        float g2h[32];
#pragma unroll
        for (int j = 0; j < 32; ++j) g2h[j] = 0.0f;
#pragma unroll
        for (int k = 0; k < 64; ++k) {
            const float e = g[k];
#pragma unroll
            for (int j = 0; j < 32; ++j) g2h[j] = fmaf(e, wr2[k * 64 + j0 + j], g2h[j]);
        }
#pragma unroll
        for (int j = 0; j < 32; ++j) {
            const float e = relu_f(g2h[j]);
            r0 = fmaf(e, wr3[(j0 + j) * 3 + 0], r0);
            r1 = fmaf(e, wr3[(j0 + j) * 3 + 1], r1);
            r2 = fmaf(e, wr3[(j0 + j) * 3 + 2], r2);
        }
    }

    out[3 * (size_t)i + 0] = 1.0f / (1.0f + __expf(-r0));
    out[3 * (size_t)i + 1] = 1.0f / (1.0f + __expf(-r1));
    out[3 * (size_t)i + 2] = 1.0f / (1.0f + __expf(-r2));
}

extern "C" void kernel_launch(void* const* d_in, const int* in_sizes, int n_in,
                              void* d_out, int out_size, void* d_ws, size_t ws_size,
                              hipStream_t stream)
{
    const float* xyz   = (const float*)d_in[0];
    const float* dirv  = (const float*)d_in[1];
    const float* table = (const float*)d_in[2];
    const float* ws1   = (const float*)d_in[3];
    const float* ws2   = (const float*)d_in[4];
    const float* wr1   = (const float*)d_in[5];
    const float* wr2   = (const float*)d_in[6];
    const float* wr3   = (const float*)d_in[7];
    float* out = (float*)d_out;

    const int n = in_sizes[0] / 3;
    const int blocks_per_level = (n + 255) / 256;
    dim3 block(256);
    dim3 grid_mlp(blocks_per_level);
    dim3 grid_enc(8 * blocks_per_level);

    const size_t enc_bytes = (size_t)n * 16 * sizeof(float2);   // 268 MB at n=2^21
    if (ws_size >= enc_bytes && (n & 255) == 0) {
        float* ws_enc = (float*)d_ws;
        // pass A: hashed levels 5..12, one per XCD (4 MB table == 4 MB L2)
        hipLaunchKernelGGL(encode_pinned, grid_enc, block, 0, stream,
                           xyz, table, ws_enc, 0xCBA98765u, n);
        // pass B: levels 13,14,15 on XCDs 0..2; dense 0..4 on XCDs 3..7
        hipLaunchKernelGGL(encode_pinned, grid_enc, block, 0, stream,
                           xyz, table, ws_enc, 0x43210FEDu, n);
        hipLaunchKernelGGL(mlp_mfma, grid_mlp, block, 0, stream,
                           ws_enc, dirv, ws1, ws2, wr1, wr2, wr3, out, n);
    } else {
        hipLaunchKernelGGL(nerf_fused, grid_mlp, block, 0, stream,
                           xyz, dirv, table, ws1, ws2, wr1, wr2, wr3, out, n);
    }
}